// Round 6
// baseline (31.496 us; speedup 1.0000x reference)
//
#include <hip/hip_runtime.h>

// Problem constants (match reference)
#define BATCH      8192
#define D_DIM      512
#define NUM_CLS    90
#define K_CENTERS  8

typedef float v4f __attribute__((ext_vector_type(4)));

// Single compute kernel: 512 blocks x 1024 threads; 16 waves/block, one wave per sample.
// Lane layout: k = lane & 7 (which center), sub = lane >> 3 (which 64-elem chunk of D).
// Each lane: 64-elem fp32 dot via 16 float4 FMA iterations.
// Reduce over sub with shfl_xor(8,16,32); then over k with shfl_xor(1,2,4) on (d, d*d).
//
// Tail: ONE non-returning RELAXED agent-scope atomicAdd(out, p/BATCH) per block.
//  - no retirement counter, no last-block fold (R3/R4's critical-path RMW burst: gone)
//  - no release fence (R2's per-block buffer_wbl2 L2 sweeps: gone)
//  - adds are spread across block retirements; only the last block's single add is
//    on the critical path. Kernel-end implicit release publishes out.
// out is zeroed by a 4-byte memset node (out is re-poisoned every iteration).
__global__ __launch_bounds__(1024) void center_loss_main(
    const float* __restrict__ x,
    const float* __restrict__ centers,
    const int*   __restrict__ labels,
    float*       __restrict__ out)
{
    const int wave = threadIdx.x >> 6;   // 0..15
    const int lane = threadIdx.x & 63;
    const int k    = lane & 7;
    const int sub  = lane >> 3;

    const int b = blockIdx.x * 16 + wave;   // 0..8191

    __shared__ float s_r[16];

    const int label = labels[b];
    // v4f index: sub + 8*i -> float offset sub*4 + 32*i (contiguous 128B per iter across sub)
    const v4f* xr = (const v4f*)(x + (size_t)b * D_DIM) + sub;
    const v4f* cr = (const v4f*)(centers + ((size_t)label * K_CENTERS + k) * D_DIM) + sub;

    float acc = 0.0f;
#pragma unroll
    for (int i = 0; i < 16; ++i) {
        v4f xv = xr[i * 8];
        v4f cv = cr[i * 8];
        acc = fmaf(xv.x, cv.x, acc);
        acc = fmaf(xv.y, cv.y, acc);
        acc = fmaf(xv.z, cv.z, acc);
        acc = fmaf(xv.w, cv.w, acc);
    }
    // reduce across sub (lane bits 3..5)
    acc += __shfl_xor(acc, 8);
    acc += __shfl_xor(acc, 16);
    acc += __shfl_xor(acc, 32);

    const float dk = 1.0f + acc;     // d[b,k], replicated across sub-groups
    float s1 = dk;
    float s2 = dk * dk;
    // reduce across k (lane bits 0..2)
    s1 += __shfl_xor(s1, 1);  s2 += __shfl_xor(s2, 1);
    s1 += __shfl_xor(s1, 2);  s2 += __shfl_xor(s2, 2);
    s1 += __shfl_xor(s1, 4);  s2 += __shfl_xor(s2, 4);

    if (lane == 0) s_r[wave] = s2 / s1;   // sum_k w*d = (sum d^2) / (sum d)
    __syncthreads();

    if (threadIdx.x == 0) {
        float p = 0.0f;
#pragma unroll
        for (int i = 0; i < 16; ++i) p += s_r[i];
        // contribute this block's share of the mean; relaxed, non-returning,
        // agent scope -> plain global_atomic_add_f32 at the coherence point
        __hip_atomic_fetch_add(out, p * (1.0f / (float)BATCH),
                               __ATOMIC_RELAXED, __HIP_MEMORY_SCOPE_AGENT);
    }
}

extern "C" void kernel_launch(void* const* d_in, const int* in_sizes, int n_in,
                              void* d_out, int out_size, void* d_ws, size_t ws_size,
                              hipStream_t stream) {
    const float* x       = (const float*)d_in[0];
    const float* centers = (const float*)d_in[1];
    const int*   labels  = (const int*)d_in[2];
    float* out = (float*)d_out;

    // out is re-poisoned every iteration: zero the 4-byte accumulator first.
    hipMemsetAsync(out, 0, sizeof(float), stream);

    const int nblocks = BATCH / 16;     // 512 blocks; 16 waves/block, 1 sample/wave
    center_loss_main<<<nblocks, 1024, 0, stream>>>(x, centers, labels, out);
}

// Round 7
// 25.722 us; speedup vs baseline: 1.2245x; 1.2245x over previous
//
#include <hip/hip_runtime.h>

// Problem constants (match reference)
#define BATCH      8192
#define D_DIM      512
#define NUM_CLS    90
#define K_CENTERS  8

typedef float v4f __attribute__((ext_vector_type(4)));

// Kernel 1: 512 blocks x 1024 threads; 16 waves/block, one wave (64 lanes) per sample.
// Lane layout: k = lane & 7 (which center), sub = lane >> 3 (which 64-elem chunk of D).
// Each lane: 64-elem fp32 dot via 16 float4 FMA iterations.
// Reduce over sub with shfl_xor(8,16,32); then over k with shfl_xor(1,2,4) on (d, d*d).
// Per-block: 16 wave results -> LDS -> one float partial, plain store.
//
// Structure note (rounds 2-4, 6): every fused-tail alternative -- fenced atomics
// (56.8 us), fence-free slot+counter (32.4), store+counter (40.6), single
// atomicAdd+memset node (31.5) -- loses to this plain two-kernel form (25.9).
// On this graph-replay harness a dependent micro-launch is cheaper than any
// added memset node or device-scope RMW path. Do not re-fuse.
__global__ __launch_bounds__(1024) void center_loss_main(
    const float* __restrict__ x,
    const float* __restrict__ centers,
    const int*   __restrict__ labels,
    float*       __restrict__ partials)
{
    const int wave = threadIdx.x >> 6;   // 0..15
    const int lane = threadIdx.x & 63;
    const int k    = lane & 7;
    const int sub  = lane >> 3;

    const int b = blockIdx.x * 16 + wave;   // 0..8191

    __shared__ float s_r[16];

    const int label = labels[b];
    // v4f index: sub + 8*i -> float offset sub*4 + 32*i (contiguous 128B per iter across sub)
    const v4f* xr = (const v4f*)(x + (size_t)b * D_DIM) + sub;
    const v4f* cr = (const v4f*)(centers + ((size_t)label * K_CENTERS + k) * D_DIM) + sub;

    float acc = 0.0f;
#pragma unroll
    for (int i = 0; i < 16; ++i) {
        v4f xv = xr[i * 8];
        v4f cv = cr[i * 8];
        acc = fmaf(xv.x, cv.x, acc);
        acc = fmaf(xv.y, cv.y, acc);
        acc = fmaf(xv.z, cv.z, acc);
        acc = fmaf(xv.w, cv.w, acc);
    }
    // reduce across sub (lane bits 3..5)
    acc += __shfl_xor(acc, 8);
    acc += __shfl_xor(acc, 16);
    acc += __shfl_xor(acc, 32);

    const float dk = 1.0f + acc;     // d[b,k], replicated across sub-groups
    float s1 = dk;
    float s2 = dk * dk;
    // reduce across k (lane bits 0..2)
    s1 += __shfl_xor(s1, 1);  s2 += __shfl_xor(s2, 1);
    s1 += __shfl_xor(s1, 2);  s2 += __shfl_xor(s2, 2);
    s1 += __shfl_xor(s1, 4);  s2 += __shfl_xor(s2, 4);

    if (lane == 0) s_r[wave] = s2 / s1;   // sum_k w*d = (sum d^2) / (sum d)
    __syncthreads();

    if (threadIdx.x == 0) {
        float p = 0.0f;
#pragma unroll
        for (int i = 0; i < 16; ++i) p += s_r[i];
        partials[blockIdx.x] = p;
    }
}

// Kernel 2: single-wave reduction of 512 float partials -> float mean.
// No LDS, no __syncthreads: 64 lanes x 2 float4 loads (one latency round),
// double accumulate, 6 shuffles, one store.
__global__ __launch_bounds__(64) void center_loss_reduce(
    const float* __restrict__ partials,
    float*       __restrict__ out)
{
    const int lane = threadIdx.x;   // 0..63
    const v4f* p4 = (const v4f*)partials;

    v4f a = p4[lane];          // floats [4*lane, 4*lane+4)
    v4f b = p4[lane + 64];     // floats [256 + 4*lane, ...)

    double s = (double)a.x + (double)a.y + (double)a.z + (double)a.w
             + (double)b.x + (double)b.y + (double)b.z + (double)b.w;

    s += __shfl_xor(s, 1);
    s += __shfl_xor(s, 2);
    s += __shfl_xor(s, 4);
    s += __shfl_xor(s, 8);
    s += __shfl_xor(s, 16);
    s += __shfl_xor(s, 32);

    if (lane == 0) out[0] = (float)(s / (double)BATCH);
}

extern "C" void kernel_launch(void* const* d_in, const int* in_sizes, int n_in,
                              void* d_out, int out_size, void* d_ws, size_t ws_size,
                              hipStream_t stream) {
    const float* x       = (const float*)d_in[0];
    const float* centers = (const float*)d_in[1];
    const int*   labels  = (const int*)d_in[2];
    float* out      = (float*)d_out;
    float* partials = (float*)d_ws;     // 512 floats = 2 KB

    const int nblocks = BATCH / 16;     // 512 blocks; 16 waves/block, 1 sample/wave
    center_loss_main<<<nblocks, 1024, 0, stream>>>(x, centers, labels, partials);
    center_loss_reduce<<<1, 64, 0, stream>>>(partials, out);
}